// Round 5
// baseline (802.054 us; speedup 1.0000x reference)
//
#include <hip/hip_runtime.h>
#include <hip/hip_cooperative_groups.h>
#include <math.h>

namespace cg = cooperative_groups;

// GraphAttentionLayer, N=8192, D=256, fp32. Exact reformulation:
//   h = x@W + b ; s1 = h@a1 ; s2 = h@a2 ; c_i = s1_i + a_b
//   row_i = [ A_i * Suf(E h)(r_i) + Alo_i * Pre(F h)(r_i) ] / [ A_i * sufE(r_i) + Alo_i * preF(r_i) ]
//   where E_j=exp(s2_j), F_j=exp(.01 s2_j), A=exp(c), Alo=exp(.01c),
//   r_i = lower_bound(sorted s2, -c_i)  (exact split: z>=0 vs z<0 of leaky_relu).
// R4 (resubmit; prior round timed out before measuring): exact within-bucket
// ranking -> globally sorted s2s; E/F on the fly; mid-pipeline fused into ONE
// cooperative kernel with h rows held in registers across grid syncs (h read
// once). Fallback: 8 phase-sliced launches.

#define NN 8192
#define DD 256
#define NB 8192
#define CH 512
#define POS (NN / CH)    /* 16 */
#define RANGE 8.0f
#define SCALE (NB / (2.0f * RANGE))
#define NEG_SLOPE 0.01f

__device__ __forceinline__ int bucket_of(float v) {
    v = fminf(fmaxf(v, -RANGE), RANGE);
    int b = (int)floorf((v + RANGE) * SCALE);
    if (b < 0) b = 0;
    if (b > NB - 1) b = NB - 1;
    return b;
}

// ---------------------------------------------------------------- KA: h = x@W+b, s1, s2, hist
__global__ __launch_bounds__(256) void ka_gemm(
    const float* __restrict__ x, const float* __restrict__ W,
    const float* __restrict__ bfc, const float* __restrict__ a1,
    const float* __restrict__ a2,
    float* __restrict__ h, float* __restrict__ s1, float* __restrict__ s2,
    int* __restrict__ cnt)
{
    const int t = threadIdx.x;
    const int ct = t & 63;
    const int rt = t >> 6;
    const int row0 = blockIdx.x * 16;
    __shared__ float xs[16][DD];

#pragma unroll
    for (int i = 0; i < 4; ++i) {
        const int f = i * 256 + t;
        const int r = f >> 6, c4 = f & 63;
        *reinterpret_cast<float4*>(&xs[r][c4 * 4]) =
            *reinterpret_cast<const float4*>(&x[(size_t)(row0 + r) * DD + c4 * 4]);
    }
    __syncthreads();

    float acc[4][4];
#pragma unroll
    for (int r = 0; r < 4; ++r)
#pragma unroll
        for (int c = 0; c < 4; ++c) acc[r][c] = 0.f;

#pragma unroll 2
    for (int k4 = 0; k4 < DD / 4; ++k4) {
        float4 wv[4];
#pragma unroll
        for (int kk = 0; kk < 4; ++kk)
            wv[kk] = *reinterpret_cast<const float4*>(&W[(size_t)(k4 * 4 + kk) * DD + ct * 4]);
        float4 xr[4];
#pragma unroll
        for (int r = 0; r < 4; ++r)
            xr[r] = *reinterpret_cast<const float4*>(&xs[rt * 4 + r][k4 * 4]);
#pragma unroll
        for (int kk = 0; kk < 4; ++kk) {
#pragma unroll
            for (int r = 0; r < 4; ++r) {
                const float xv = (kk == 0) ? xr[r].x : (kk == 1) ? xr[r].y : (kk == 2) ? xr[r].z : xr[r].w;
                acc[r][0] = fmaf(xv, wv[kk].x, acc[r][0]);
                acc[r][1] = fmaf(xv, wv[kk].y, acc[r][1]);
                acc[r][2] = fmaf(xv, wv[kk].z, acc[r][2]);
                acc[r][3] = fmaf(xv, wv[kk].w, acc[r][3]);
            }
        }
    }

    const float4 bv  = *reinterpret_cast<const float4*>(&bfc[ct * 4]);
    const float4 a1v = *reinterpret_cast<const float4*>(&a1[ct * 4]);
    const float4 a2v = *reinterpret_cast<const float4*>(&a2[ct * 4]);
    const int lane = t & 63;

#pragma unroll
    for (int r = 0; r < 4; ++r) {
        acc[r][0] += bv.x; acc[r][1] += bv.y; acc[r][2] += bv.z; acc[r][3] += bv.w;
        const int row = row0 + rt * 4 + r;
        float4 hv = make_float4(acc[r][0], acc[r][1], acc[r][2], acc[r][3]);
        *reinterpret_cast<float4*>(&h[(size_t)row * DD + ct * 4]) = hv;
        float v1 = acc[r][0] * a1v.x + acc[r][1] * a1v.y + acc[r][2] * a1v.z + acc[r][3] * a1v.w;
        float v2 = acc[r][0] * a2v.x + acc[r][1] * a2v.y + acc[r][2] * a2v.z + acc[r][3] * a2v.w;
#pragma unroll
        for (int off = 32; off; off >>= 1) {
            v1 += __shfl_xor(v1, off, 64);
            v2 += __shfl_xor(v2, off, 64);
        }
        if (lane == 0) {
            s1[row] = v1;
            s2[row] = v2;
            atomicAdd(&cnt[bucket_of(v2)], 1);
        }
    }
}

// ---------------------------------------------------------------- 512-element exclusive scan, 256 threads
__device__ __forceinline__ void scan512_excl(float* lds, float* tmp, int t)
{
    const float a0 = lds[2 * t], a1 = lds[2 * t + 1];
    tmp[t] = a0 + a1;
    __syncthreads();
    for (int off = 1; off < 256; off <<= 1) {
        const float v = (t >= off) ? tmp[t - off] : 0.f;
        __syncthreads();
        tmp[t] += v;
        __syncthreads();
    }
    const float base = (t > 0) ? tmp[t - 1] : 0.f;
    lds[2 * t] = base;         // exclusive at position 2t
    lds[2 * t + 1] = base + a0;
    __syncthreads();           // tmp[255] = total, stable after this
}

// ---------------------------------------------------------------- KMID: fused mid-pipeline
// phase < 0  => cooperative single launch (grid 512x256), phases separated by grid.sync()
// phase >= 0 => run only that phase (ordinary launch, grid per phase)
__global__ __launch_bounds__(256) void kmid(
    int phase,
    const float* __restrict__ h, const float* __restrict__ s2,
    int* __restrict__ cnt, int* __restrict__ boff, int* __restrict__ exclT,
    int* __restrict__ scanTmp, int* __restrict__ perm, int* __restrict__ perm2,
    float* __restrict__ s2s,
    float* __restrict__ TE, float* __restrict__ TF,
    float* __restrict__ sTE, float* __restrict__ sTF,
    float* __restrict__ PSE, float* __restrict__ PSF,
    float* __restrict__ psE, float* __restrict__ psF)
{
    const bool coop = (phase < 0);
    cg::grid_group grid = cg::this_grid();
    const int t = threadIdx.x;
    const int b = blockIdx.x;

    __shared__ int   idsS[256];
    __shared__ float lds[CH];
    __shared__ float tmp[256];
    __shared__ float vE[POS], vF[POS];
    __shared__ int   jj[POS];

    // ---- A1: 32 blocks scan 256 counters each -> exclT + block totals
    if (coop || phase == 0) {
        if (b < 32) {
            const int g = b * 256 + t;
            const int myCnt = cnt[g];
            idsS[t] = myCnt;
            __syncthreads();
            for (int off = 1; off < 256; off <<= 1) {
                const int v = (t >= off) ? idsS[t - off] : 0;
                __syncthreads();
                idsS[t] += v;
                __syncthreads();
            }
            exclT[g] = idsS[t] - myCnt;
            if (t == 255) scanTmp[b] = idsS[255];
        }
    }
    if (coop) { __threadfence(); grid.sync(); }

    // ---- A2: scan the 32 block totals
    if (coop || phase == 1) {
        if (b == 0 && t == 0) {
            int run = 0;
            for (int k = 0; k < 32; ++k) { const int v = scanTmp[k]; scanTmp[k] = run; run += v; }
        }
    }
    if (coop) { __threadfence(); grid.sync(); }

    // ---- A3: boff + cursor
    if (coop || phase == 2) {
        if (b < 32) {
            const int g = b * 256 + t;
            const int val = scanTmp[b] + exclT[g];
            boff[g] = val;
            cnt[g] = val;
            if (g == 0) boff[NB] = NN;
        }
    }
    if (coop) { __threadfence(); grid.sync(); }

    // ---- B: scatter into buckets (arbitrary order within bucket)
    if (coop || phase == 3) {
        if (b < 32) {
            const int j = b * 256 + t;
            const int bk = bucket_of(s2[j]);
            const int p = atomicAdd(&cnt[bk], 1);
            perm[p] = j;
        }
    }
    if (coop) { __threadfence(); grid.sync(); }

    // ---- C: exact within-bucket rank -> perm2 (value-sorted), s2s (sorted values)
    if (coop || phase == 4) {
        if (b < 32) {
            const int j = b * 256 + t;
            const float v = s2[j];
            const int bk = bucket_of(v);
            const int p0 = boff[bk], p1 = boff[bk + 1];
            int rank = 0;
            for (int p = p0; p < p1; ++p) {
                const int k = perm[p];
                const float vk = s2[k];
                rank += (vk < v) || (vk == v && k < j);
            }
            const int pos = p0 + rank;
            perm2[pos] = j;
            s2s[pos] = v;
        }
    }
    if (coop) { __threadfence(); grid.sync(); }

    // ---- D: per-chunk totals; h rows cached in registers
    float hv[POS];
    const int c = b;
    if (coop || phase == 5) {
        if (t < POS) {
            const float v = s2s[c * POS + t];
            jj[t] = perm2[c * POS + t];
            vE[t] = expf(v);
            vF[t] = expf(NEG_SLOPE * v);
        }
        __syncthreads();
#pragma unroll
        for (int k = 0; k < POS; ++k) hv[k] = h[(size_t)jj[k] * DD + t];
        float te = 0.f, tf = 0.f;
#pragma unroll
        for (int k = 0; k < POS; ++k) { te = fmaf(vE[k], hv[k], te); tf = fmaf(vF[k], hv[k], tf); }
        TE[c * DD + t] = te;
        TF[c * DD + t] = tf;
        if (t == 0) {
            float se = 0.f, sf = 0.f;
#pragma unroll
            for (int k = 0; k < POS; ++k) { se += vE[k]; sf += vF[k]; }
            sTE[c] = se; sTF[c] = sf;
        }
    }
    if (coop) { __threadfence(); grid.sync(); }

    // ---- E: chunk-level scans (suffix for E, prefix for F), in place -> exclusive bases
    if (coop || phase == 6) {
        const bool isE = (b < 256);
        const int d = isE ? b : (b - 256);
        const int q0 = 2 * t, q1 = 2 * t + 1;
        if (isE) { lds[q0] = TE[(size_t)(511 - q0) * DD + d]; lds[q1] = TE[(size_t)(511 - q1) * DD + d]; }
        else     { lds[q0] = TF[(size_t)q0 * DD + d];         lds[q1] = TF[(size_t)q1 * DD + d]; }
        __syncthreads();
        scan512_excl(lds, tmp, t);
        if (isE) {
            TE[(size_t)(511 - q0) * DD + d] = lds[q0];
            TE[(size_t)(511 - q1) * DD + d] = lds[q1];
            if (t == 0) PSE[(size_t)NN * DD + d] = 0.f;
        } else {
            TF[(size_t)q0 * DD + d] = lds[q0];
            TF[(size_t)q1 * DD + d] = lds[q1];
            if (t == 0) PSF[(size_t)NN * DD + d] = tmp[255];
        }
        __syncthreads();
        if (b == 0) {          // scalar suffix scan of sTE
            lds[q0] = sTE[511 - q0]; lds[q1] = sTE[511 - q1];
            __syncthreads();
            scan512_excl(lds, tmp, t);
            sTE[511 - q0] = lds[q0]; sTE[511 - q1] = lds[q1];
            if (t == 0) psE[NN] = 0.f;
        } else if (b == 256) { // scalar prefix scan of sTF
            lds[q0] = sTF[q0]; lds[q1] = sTF[q1];
            __syncthreads();
            scan512_excl(lds, tmp, t);
            sTF[q0] = lds[q0]; sTF[q1] = lds[q1];
            if (t == 0) psF[NN] = tmp[255];
        }
    }
    if (coop) { __threadfence(); grid.sync(); }

    // ---- F: write position-indexed PSE/PSF (+ scalar psE/psF)
    if (coop || phase == 7) {
        if (!coop) {
            if (t < POS) {
                const float v = s2s[c * POS + t];
                jj[t] = perm2[c * POS + t];
                vE[t] = expf(v);
                vF[t] = expf(NEG_SLOPE * v);
            }
            __syncthreads();
#pragma unroll
            for (int k = 0; k < POS; ++k) hv[k] = h[(size_t)jj[k] * DD + t];
        }
        float runE = TE[c * DD + t];
#pragma unroll
        for (int k = POS - 1; k >= 0; --k) {
            runE = fmaf(vE[k], hv[k], runE);
            PSE[(size_t)(c * POS + k) * DD + t] = runE;
        }
        float runF = TF[c * DD + t];
#pragma unroll
        for (int k = 0; k < POS; ++k) {
            PSF[(size_t)(c * POS + k) * DD + t] = runF;
            runF = fmaf(vF[k], hv[k], runF);
        }
        if (t == 0) {
            float rE = sTE[c];
#pragma unroll
            for (int k = POS - 1; k >= 0; --k) { rE += vE[k]; psE[c * POS + k] = rE; }
            float rF = sTF[c];
#pragma unroll
            for (int k = 0; k < POS; ++k) { psF[c * POS + k] = rF; rF += vF[k]; }
        }
    }
}

// ---------------------------------------------------------------- KE: output rows (no boundary fixup)
__global__ __launch_bounds__(256) void ke_out(
    const float* __restrict__ s1, const float* __restrict__ s2s,
    const float* __restrict__ PSE, const float* __restrict__ PSF,
    const float* __restrict__ psE, const float* __restrict__ psF,
    const float* __restrict__ ab, float* __restrict__ out)
{
    const int i = blockIdx.x;
    const int t = threadIdx.x;
    const float c = s1[i] + ab[0];
    const float tau = -c;
    const float A = expf(c);
    const float Alo = expf(NEG_SLOPE * c);

    int lo = 0, hi = NN;                 // r = lower_bound(s2s, tau)
    while (lo < hi) {
        const int mid = (lo + hi) >> 1;
        const bool lt = (s2s[mid] < tau);
        lo = lt ? (mid + 1) : lo;
        hi = lt ? hi : mid;
    }
    const float num = fmaf(A, PSE[(size_t)lo * DD + t], Alo * PSF[(size_t)lo * DD + t]);
    const float den = fmaf(A, psE[lo], Alo * psF[lo]);
    out[(size_t)i * DD + t] = num / den;
}

// ----------------------------------------------------------------
extern "C" void kernel_launch(void* const* d_in, const int* in_sizes, int n_in,
                              void* d_out, int out_size, void* d_ws, size_t ws_size,
                              hipStream_t stream)
{
    const float* x   = (const float*)d_in[0];
    const float* W   = (const float*)d_in[1];
    const float* bfc = (const float*)d_in[2];
    const float* a1  = (const float*)d_in[3];
    const float* a2  = (const float*)d_in[4];
    const float* ab  = (const float*)d_in[5];
    float* out = (float*)d_out;

    float* h    = (float*)d_ws;                    // [N][D]
    float* PSE  = h + (size_t)NN * DD;             // [N+1][D]
    float* PSF  = PSE + (size_t)(NN + 1) * DD;     // [N+1][D]
    float* TE   = PSF + (size_t)(NN + 1) * DD;     // [CH][D]
    float* TF   = TE + (size_t)CH * DD;            // [CH][D]
    float* s1   = TF + (size_t)CH * DD;            // [N]
    float* s2   = s1 + NN;                         // [N]
    float* s2s  = s2 + NN;                         // [N]
    float* psE  = s2s + NN;                        // [N+1]
    float* psF  = psE + (NN + 1);                  // [N+1]
    float* sTE  = psF + (NN + 1);                  // [CH]
    float* sTF  = sTE + CH;                        // [CH]
    int* cnt    = (int*)(sTF + CH);                // [NB]
    int* boff   = cnt + NB;                        // [NB+1]
    int* exclT  = boff + (NB + 1);                 // [NB]
    int* perm   = exclT + NB;                      // [N]
    int* perm2  = perm + NN;                       // [N]
    int* scanTmp= perm2 + NN;                      // [32]

    hipMemsetAsync(cnt, 0, NB * sizeof(int), stream);
    ka_gemm<<<NN / 16, 256, 0, stream>>>(x, W, bfc, a1, a2, h, s1, s2, cnt);

    // mid-pipeline: one cooperative kernel; fall back to 8 phase launches on error
    {
        int phase = -1;
        const float* h_ = h; const float* s2_ = s2;
        int* cnt_ = cnt; int* boff_ = boff; int* exclT_ = exclT; int* scanTmp_ = scanTmp;
        int* perm_ = perm; int* perm2_ = perm2; float* s2s_ = s2s;
        float* TE_ = TE; float* TF_ = TF; float* sTE_ = sTE; float* sTF_ = sTF;
        float* PSE_ = PSE; float* PSF_ = PSF; float* psE_ = psE; float* psF_ = psF;
        void* args[] = { &phase, &h_, &s2_, &cnt_, &boff_, &exclT_, &scanTmp_,
                         &perm_, &perm2_, &s2s_, &TE_, &TF_, &sTE_, &sTF_,
                         &PSE_, &PSF_, &psE_, &psF_ };
        hipError_t err = hipLaunchCooperativeKernel(reinterpret_cast<void*>(kmid),
                                                    dim3(CH), dim3(256), args, 0, stream);
        if (err != hipSuccess) {
            kmid<<<32,  256, 0, stream>>>(0, h, s2, cnt, boff, exclT, scanTmp, perm, perm2, s2s, TE, TF, sTE, sTF, PSE, PSF, psE, psF);
            kmid<<<1,   256, 0, stream>>>(1, h, s2, cnt, boff, exclT, scanTmp, perm, perm2, s2s, TE, TF, sTE, sTF, PSE, PSF, psE, psF);
            kmid<<<32,  256, 0, stream>>>(2, h, s2, cnt, boff, exclT, scanTmp, perm, perm2, s2s, TE, TF, sTE, sTF, PSE, PSF, psE, psF);
            kmid<<<32,  256, 0, stream>>>(3, h, s2, cnt, boff, exclT, scanTmp, perm, perm2, s2s, TE, TF, sTE, sTF, PSE, PSF, psE, psF);
            kmid<<<32,  256, 0, stream>>>(4, h, s2, cnt, boff, exclT, scanTmp, perm, perm2, s2s, TE, TF, sTE, sTF, PSE, PSF, psE, psF);
            kmid<<<CH,  256, 0, stream>>>(5, h, s2, cnt, boff, exclT, scanTmp, perm, perm2, s2s, TE, TF, sTE, sTF, PSE, PSF, psE, psF);
            kmid<<<CH,  256, 0, stream>>>(6, h, s2, cnt, boff, exclT, scanTmp, perm, perm2, s2s, TE, TF, sTE, sTF, PSE, PSF, psE, psF);
            kmid<<<CH,  256, 0, stream>>>(7, h, s2, cnt, boff, exclT, scanTmp, perm, perm2, s2s, TE, TF, sTE, sTF, PSE, PSF, psE, psF);
        }
    }

    ke_out<<<NN, 256, 0, stream>>>(s1, s2s, PSE, PSF, psE, psF, ab, out);
}

// Round 9
// 142.894 us; speedup vs baseline: 5.6129x; 5.6129x over previous
//
#include <hip/hip_runtime.h>
#include <math.h>

// GraphAttentionLayer, N=8192, D=256, fp32. Exact reformulation:
//   h = x@W + b ; s1 = h@a1 ; s2 = h@a2 ; c_i = s1_i + a_b
//   out_i = [A_i*SufEH(r_i) + Alo_i*PreFH(r_i)] / [A_i*sufE(r_i) + Alo_i*preF(r_i)]
//   E_j=exp(s2_j), F_j=exp(.01*s2_j), A=exp(c), Alo=exp(.01c),
//   r_i = lower_bound(sorted s2, -c_i)   (exact leaky_relu split).
// R6 resubmit #3 (acquisition timeouts / container failures; never measured).
// NO cooperative kernel (R5 post-mortem: grid.sync() ~100us/sync on 8-XCD
// MI355X -> 683us). Discrete launches; PSE/PSF arrays eliminated — ke
// reconstructs split-point sums from chunk bases TE/TF + <=16 in-chunk h rows
// (wave-per-row, float4-coalesced, L2-hot). h read by kd1 and ke only.

#define NN 8192
#define DD 256
#define NB 8192
#define CH 512
#define POS (NN / CH)    /* 16 */
#define RANGE 8.0f
#define SCALE (NB / (2.0f * RANGE))
#define NEG_SLOPE 0.01f

__device__ __forceinline__ int bucket_of(float v) {
    v = fminf(fmaxf(v, -RANGE), RANGE);
    int b = (int)floorf((v + RANGE) * SCALE);
    if (b < 0) b = 0;
    if (b > NB - 1) b = NB - 1;
    return b;
}

// ---------------------------------------------------------------- KA: h = x@W+b, s1, s2, hist
__global__ __launch_bounds__(256) void ka_gemm(
    const float* __restrict__ x, const float* __restrict__ W,
    const float* __restrict__ bfc, const float* __restrict__ a1,
    const float* __restrict__ a2,
    float* __restrict__ h, float* __restrict__ s1, float* __restrict__ s2,
    int* __restrict__ cnt)
{
    const int t = threadIdx.x;
    const int ct = t & 63;
    const int rt = t >> 6;
    const int row0 = blockIdx.x * 16;
    __shared__ float xs[16][DD];

#pragma unroll
    for (int i = 0; i < 4; ++i) {
        const int f = i * 256 + t;
        const int r = f >> 6, c4 = f & 63;
        *reinterpret_cast<float4*>(&xs[r][c4 * 4]) =
            *reinterpret_cast<const float4*>(&x[(size_t)(row0 + r) * DD + c4 * 4]);
    }
    __syncthreads();

    float acc[4][4];
#pragma unroll
    for (int r = 0; r < 4; ++r)
#pragma unroll
        for (int c = 0; c < 4; ++c) acc[r][c] = 0.f;

#pragma unroll 2
    for (int k4 = 0; k4 < DD / 4; ++k4) {
        float4 wv[4];
#pragma unroll
        for (int kk = 0; kk < 4; ++kk)
            wv[kk] = *reinterpret_cast<const float4*>(&W[(size_t)(k4 * 4 + kk) * DD + ct * 4]);
        float4 xr[4];
#pragma unroll
        for (int r = 0; r < 4; ++r)
            xr[r] = *reinterpret_cast<const float4*>(&xs[rt * 4 + r][k4 * 4]);
#pragma unroll
        for (int kk = 0; kk < 4; ++kk) {
#pragma unroll
            for (int r = 0; r < 4; ++r) {
                const float xv = (kk == 0) ? xr[r].x : (kk == 1) ? xr[r].y : (kk == 2) ? xr[r].z : xr[r].w;
                acc[r][0] = fmaf(xv, wv[kk].x, acc[r][0]);
                acc[r][1] = fmaf(xv, wv[kk].y, acc[r][1]);
                acc[r][2] = fmaf(xv, wv[kk].z, acc[r][2]);
                acc[r][3] = fmaf(xv, wv[kk].w, acc[r][3]);
            }
        }
    }

    const float4 bv  = *reinterpret_cast<const float4*>(&bfc[ct * 4]);
    const float4 a1v = *reinterpret_cast<const float4*>(&a1[ct * 4]);
    const float4 a2v = *reinterpret_cast<const float4*>(&a2[ct * 4]);
    const int lane = t & 63;

#pragma unroll
    for (int r = 0; r < 4; ++r) {
        acc[r][0] += bv.x; acc[r][1] += bv.y; acc[r][2] += bv.z; acc[r][3] += bv.w;
        const int row = row0 + rt * 4 + r;
        float4 hv = make_float4(acc[r][0], acc[r][1], acc[r][2], acc[r][3]);
        *reinterpret_cast<float4*>(&h[(size_t)row * DD + ct * 4]) = hv;
        float v1 = acc[r][0] * a1v.x + acc[r][1] * a1v.y + acc[r][2] * a1v.z + acc[r][3] * a1v.w;
        float v2 = acc[r][0] * a2v.x + acc[r][1] * a2v.y + acc[r][2] * a2v.z + acc[r][3] * a2v.w;
#pragma unroll
        for (int off = 32; off; off >>= 1) {
            v1 += __shfl_xor(v1, off, 64);
            v2 += __shfl_xor(v2, off, 64);
        }
        if (lane == 0) {
            s1[row] = v1;
            s2[row] = v2;
            atomicAdd(&cnt[bucket_of(v2)], 1);
        }
    }
}

// ---------------------------------------------------------------- KB: exclusive scan cnt -> boff (+cursor)
__global__ __launch_bounds__(256) void kb_scan(int* __restrict__ cnt, int* __restrict__ boff)
{
    __shared__ int lds[256];
    const int t = threadIdx.x;
    const int base = t * 32;
    int loc[32];
    int s = 0;
#pragma unroll
    for (int k = 0; k < 32; ++k) { loc[k] = s; s += cnt[base + k]; }
    lds[t] = s;
    __syncthreads();
    for (int off = 1; off < 256; off <<= 1) {
        const int v = (t >= off) ? lds[t - off] : 0;
        __syncthreads();
        lds[t] += v;
        __syncthreads();
    }
    const int excl = (t > 0) ? lds[t - 1] : 0;
#pragma unroll
    for (int k = 0; k < 32; ++k) {
        const int val = excl + loc[k];
        boff[base + k] = val;
        cnt[base + k] = val; // scatter cursor
    }
    if (t == 0) boff[NB] = NN;
}

// ---------------------------------------------------------------- KC: counting-sort scatter
__global__ __launch_bounds__(256) void kc_scatter(
    const float* __restrict__ s2, int* __restrict__ cursor, int* __restrict__ perm)
{
    const int j = blockIdx.x * blockDim.x + threadIdx.x;
    if (j < NN) {
        const int b = bucket_of(s2[j]);
        const int p = atomicAdd(&cursor[b], 1);
        perm[p] = j;
    }
}

// ---------------------------------------------------------------- KC2: exact within-bucket rank -> perm2, s2s
__global__ __launch_bounds__(256) void kc2_rank(
    const float* __restrict__ s2, const int* __restrict__ perm,
    const int* __restrict__ boff, int* __restrict__ perm2, float* __restrict__ s2s)
{
    const int j = blockIdx.x * blockDim.x + threadIdx.x;
    if (j < NN) {
        const float v = s2[j];
        const int bk = bucket_of(v);
        const int p0 = boff[bk], p1 = boff[bk + 1];
        int rank = 0;
        for (int p = p0; p < p1; ++p) {
            const int k = perm[p];
            const float vk = s2[k];
            rank += (vk < v) || (vk == v && k < j);
        }
        const int pos = p0 + rank;
        perm2[pos] = j;
        s2s[pos] = v;
    }
}

// ---------------------------------------------------------------- KD1: per-chunk totals, wave-per-chunk
// 128 blocks x 256 thr = 512 waves; wave w of block b owns chunk c = b*4+w.
__global__ __launch_bounds__(256) void kd1_tot(
    const float* __restrict__ h, const int* __restrict__ perm2,
    const float* __restrict__ s2s,
    float* __restrict__ TE, float* __restrict__ TF,
    float* __restrict__ sTE, float* __restrict__ sTF)
{
    const int w = threadIdx.x >> 6, lane = threadIdx.x & 63;
    const int c = blockIdx.x * 4 + w;
    const int p0 = c * POS;
    float vE[POS], vF[POS];
    int jj[POS];
#pragma unroll
    for (int k = 0; k < POS; ++k) {
        const float v = s2s[p0 + k];
        vE[k] = expf(v);
        vF[k] = expf(NEG_SLOPE * v);
        jj[k] = perm2[p0 + k];
    }
    float4 te = make_float4(0.f, 0.f, 0.f, 0.f);
    float4 tf = make_float4(0.f, 0.f, 0.f, 0.f);
#pragma unroll
    for (int k = 0; k < POS; ++k) {
        const float4 hv = *reinterpret_cast<const float4*>(&h[(size_t)jj[k] * DD + lane * 4]);
        te.x = fmaf(vE[k], hv.x, te.x); te.y = fmaf(vE[k], hv.y, te.y);
        te.z = fmaf(vE[k], hv.z, te.z); te.w = fmaf(vE[k], hv.w, te.w);
        tf.x = fmaf(vF[k], hv.x, tf.x); tf.y = fmaf(vF[k], hv.y, tf.y);
        tf.z = fmaf(vF[k], hv.z, tf.z); tf.w = fmaf(vF[k], hv.w, tf.w);
    }
    *reinterpret_cast<float4*>(&TE[(size_t)c * DD + lane * 4]) = te;
    *reinterpret_cast<float4*>(&TF[(size_t)c * DD + lane * 4]) = tf;
    if (lane == 0) {
        float se = 0.f, sf = 0.f;
#pragma unroll
        for (int k = 0; k < POS; ++k) { se += vE[k]; sf += vF[k]; }
        sTE[c] = se; sTF[c] = sf;
    }
}

// ---------------------------------------------------------------- 512-element exclusive scan, 256 threads
__device__ __forceinline__ void scan512_excl(float* lds, float* tmp, int t)
{
    const float a0 = lds[2 * t], a1 = lds[2 * t + 1];
    tmp[t] = a0 + a1;
    __syncthreads();
    for (int off = 1; off < 256; off <<= 1) {
        const float v = (t >= off) ? tmp[t - off] : 0.f;
        __syncthreads();
        tmp[t] += v;
        __syncthreads();
    }
    const float base = (t > 0) ? tmp[t - 1] : 0.f;
    lds[2 * t] = base;         // exclusive at 2t
    lds[2 * t + 1] = base + a0;
    __syncthreads();           // tmp[255]=total stable after this
}

// ---------------------------------------------------------------- KD2: chunk scans -> exclusive bases (+row CH)
// b<256: suffix-scan TE col d=b. 256<=b<512: prefix-scan TF col d=b-256. b==512: scalars.
__global__ __launch_bounds__(256) void kd2_scan(
    float* __restrict__ TE, float* __restrict__ TF,
    float* __restrict__ sTE, float* __restrict__ sTF)
{
    const int t = threadIdx.x;
    const int b = blockIdx.x;
    __shared__ float lds[CH];
    __shared__ float tmp[256];
    const int q0 = 2 * t, q1 = 2 * t + 1;

    if (b < 256) {
        const int d = b;
        lds[q0] = TE[(size_t)(511 - q0) * DD + d];
        lds[q1] = TE[(size_t)(511 - q1) * DD + d];
        __syncthreads();
        scan512_excl(lds, tmp, t);
        TE[(size_t)(511 - q0) * DD + d] = lds[q0];
        TE[(size_t)(511 - q1) * DD + d] = lds[q1];
        if (t == 0) TE[(size_t)CH * DD + d] = 0.f;
    } else if (b < 512) {
        const int d = b - 256;
        lds[q0] = TF[(size_t)q0 * DD + d];
        lds[q1] = TF[(size_t)q1 * DD + d];
        __syncthreads();
        scan512_excl(lds, tmp, t);
        TF[(size_t)q0 * DD + d] = lds[q0];
        TF[(size_t)q1 * DD + d] = lds[q1];
        if (t == 0) TF[(size_t)CH * DD + d] = tmp[255];
    } else {
        lds[q0] = sTE[511 - q0]; lds[q1] = sTE[511 - q1];
        __syncthreads();
        scan512_excl(lds, tmp, t);
        sTE[511 - q0] = lds[q0]; sTE[511 - q1] = lds[q1];
        if (t == 0) sTE[CH] = 0.f;
        __syncthreads();
        lds[q0] = sTF[q0]; lds[q1] = sTF[q1];
        __syncthreads();
        scan512_excl(lds, tmp, t);
        sTF[q0] = lds[q0]; sTF[q1] = lds[q1];
        if (t == 0) sTF[CH] = tmp[255];
    }
}

// ---------------------------------------------------------------- KE: output rows, wave-per-row, no LDS/sync
// 2048 blocks x 256 thr; wave w handles row i = blockIdx*4+w; lane owns 4 cols.
__global__ __launch_bounds__(256) void ke_out(
    const float* __restrict__ h, const float* __restrict__ s1,
    const float* __restrict__ s2s, const int* __restrict__ perm2,
    const float* __restrict__ TE, const float* __restrict__ TF,
    const float* __restrict__ sTE, const float* __restrict__ sTF,
    const float* __restrict__ ab, float* __restrict__ out)
{
    const int w = threadIdx.x >> 6, lane = threadIdx.x & 63;
    const int i = blockIdx.x * 4 + w;
    const float c = s1[i] + ab[0];
    const float tau = -c;
    const float A = expf(c);
    const float Alo = expf(NEG_SLOPE * c);

    int lo = 0, hi = NN;                 // r = lower_bound(s2s, tau)
    while (lo < hi) {
        const int mid = (lo + hi) >> 1;
        const bool lt = (s2s[mid] < tau);
        lo = lt ? (mid + 1) : lo;
        hi = lt ? hi : mid;
    }
    const int c0 = lo >> 4;              // chunk (POS=16)
    const int m = lo & 15;               // within-chunk split

    float4 numE = *reinterpret_cast<const float4*>(&TE[(size_t)c0 * DD + lane * 4]);
    float4 numF = *reinterpret_cast<const float4*>(&TF[(size_t)c0 * DD + lane * 4]);
    float denE = sTE[c0];
    float denF = sTF[c0];

    if (c0 < CH) {
        const int p0 = c0 * POS;
#pragma unroll
        for (int k = 0; k < POS; ++k) {
            const float v = s2s[p0 + k];
            const int j = perm2[p0 + k];
            const float4 hv = *reinterpret_cast<const float4*>(&h[(size_t)j * DD + lane * 4]);
            if (k >= m) {
                const float e = expf(v);
                numE.x = fmaf(e, hv.x, numE.x); numE.y = fmaf(e, hv.y, numE.y);
                numE.z = fmaf(e, hv.z, numE.z); numE.w = fmaf(e, hv.w, numE.w);
                denE += e;
            } else {
                const float f = expf(NEG_SLOPE * v);
                numF.x = fmaf(f, hv.x, numF.x); numF.y = fmaf(f, hv.y, numF.y);
                numF.z = fmaf(f, hv.z, numF.z); numF.w = fmaf(f, hv.w, numF.w);
                denF += f;
            }
        }
    }

    const float inv = 1.f / fmaf(A, denE, Alo * denF);
    float4 o;
    o.x = fmaf(A, numE.x, Alo * numF.x) * inv;
    o.y = fmaf(A, numE.y, Alo * numF.y) * inv;
    o.z = fmaf(A, numE.z, Alo * numF.z) * inv;
    o.w = fmaf(A, numE.w, Alo * numF.w) * inv;
    *reinterpret_cast<float4*>(&out[(size_t)i * DD + lane * 4]) = o;
}

// ----------------------------------------------------------------
extern "C" void kernel_launch(void* const* d_in, const int* in_sizes, int n_in,
                              void* d_out, int out_size, void* d_ws, size_t ws_size,
                              hipStream_t stream)
{
    const float* x   = (const float*)d_in[0];
    const float* W   = (const float*)d_in[1];
    const float* bfc = (const float*)d_in[2];
    const float* a1  = (const float*)d_in[3];
    const float* a2  = (const float*)d_in[4];
    const float* ab  = (const float*)d_in[5];
    float* out = (float*)d_out;

    float* h    = (float*)d_ws;                    // [N][D]
    float* TE   = h + (size_t)NN * DD;             // [CH+1][D]
    float* TF   = TE + (size_t)(CH + 1) * DD;      // [CH+1][D]
    float* s1   = TF + (size_t)(CH + 1) * DD;      // [N]
    float* s2   = s1 + NN;                         // [N]
    float* s2s  = s2 + NN;                         // [N]
    float* sTE  = s2s + NN;                        // [CH+1]
    float* sTF  = sTE + (CH + 1);                  // [CH+1]
    int* cnt    = (int*)(sTF + (CH + 1));          // [NB]
    int* boff   = cnt + NB;                        // [NB+1]
    int* perm   = boff + (NB + 1);                 // [N]
    int* perm2  = perm + NN;                       // [N]

    hipMemsetAsync(cnt, 0, NB * sizeof(int), stream);
    ka_gemm <<<NN / 16, 256, 0, stream>>>(x, W, bfc, a1, a2, h, s1, s2, cnt);
    kb_scan <<<1, 256, 0, stream>>>(cnt, boff);
    kc_scatter<<<NN / 256, 256, 0, stream>>>(s2, cnt, perm);
    kc2_rank<<<NN / 256, 256, 0, stream>>>(s2, perm, boff, perm2, s2s);
    kd1_tot <<<CH / 4, 256, 0, stream>>>(h, perm2, s2s, TE, TF, sTE, sTF);
    kd2_scan<<<513, 256, 0, stream>>>(TE, TF, sTE, sTF);
    ke_out  <<<NN / 4, 256, 0, stream>>>(h, s1, s2s, perm2, TE, TF, sTE, sTF, ab, out);
}